// Round 6
// baseline (220.677 us; speedup 1.0000x reference)
//
#include <hip/hip_runtime.h>
#include <math.h>

#define DIM    1024
#define BATCH  2
#define SEQ    2048
#define NHEAD  16
#define HDIM   64
#define MROWS  (BATCH*SEQ)   // 4096
#define NSPLIT 8             // ktv S-splits

typedef unsigned short u16;
typedef __attribute__((ext_vector_type(8))) short  s16x8;   // 8 bf16 = 4 VGPRs
typedef __attribute__((ext_vector_type(4))) float  f32x4;

typedef __attribute__((address_space(3))) unsigned int       lds_u32_t;
typedef const __attribute__((address_space(1))) unsigned int glb_u32_t;

__device__ __forceinline__ float bf2f(u16 h) {
    unsigned u = ((unsigned)h) << 16; float f; __builtin_memcpy(&f, &u, 4); return f;
}
__device__ __forceinline__ u16 f2bf(float f) {
    unsigned u; __builtin_memcpy(&u, &f, 4);
    u += 0x7FFFu + ((u >> 16) & 1u);           // round-to-nearest-even
    return (u16)(u >> 16);
}

// ---------------------------------------------------------------------------
// Fused fp32->bf16 pack for x + 5 weights. One launch.
// ---------------------------------------------------------------------------
__global__ __launch_bounds__(256)
void pack_all(const float* __restrict__ x,
              const float* __restrict__ Wq, const float* __restrict__ Wk,
              const float* __restrict__ Wv, const float* __restrict__ W1,
              const float* __restrict__ W2,
              u16* __restrict__ xb, u16* __restrict__ Wqb, u16* __restrict__ Wkb,
              u16* __restrict__ Wvb, u16* __restrict__ W1b, u16* __restrict__ W2b)
{
    const int bid = blockIdx.x;
    const float* src; u16* dst; int i;
    if (bid < 4096) { src = x; dst = xb; i = bid * 256 + threadIdx.x; }
    else {
        const int w = (bid - 4096) >> 10;
        const int lb = (bid - 4096) & 1023;
        src = (w == 0) ? Wq : (w == 1) ? Wk : (w == 2) ? Wv : (w == 3) ? W1 : W2;
        dst = (w == 0) ? Wqb : (w == 1) ? Wkb : (w == 2) ? Wvb : (w == 3) ? W1b : W2b;
        i = lb * 256 + threadIdx.x;
    }
    float4 v = ((const float4*)src)[i];
    ushort4 o = { f2bf(v.x), f2bf(v.y), f2bf(v.z), f2bf(v.w) };
    ((ushort4*)dst)[i] = o;
}

// ---------------------------------------------------------------------------
// Double-buffered core A (round-4 proven): 256 thr = 4 waves (2x2), tile
// 128x128, wave tile 64x64 (4x4 MFMAs), BK=64 as two [128][32] panels.
// LDS 2x16 KB/operand = 64 KB -> 2 blocks/CU. One barrier per K-iter; the
// next tile's global_load_lds stay in flight across the compute phase.
// ---------------------------------------------------------------------------
__device__ __forceinline__ void stage128(const u16* __restrict__ g, int k0,
                                         u16* lds, int tid)
{
    #pragma unroll
    for (int j = 0; j < 4; ++j) {
        const int cid = j * 256 + tid;          // 0..1023 16B-chunks
        const int p   = cid >> 9;               // k-half panel
        const int r   = (cid >> 2) & 127;
        const int c2  = cid & 3;
        const u16* src = g + (size_t)r * DIM + k0 + p * 32 + c2 * 8;
        __builtin_amdgcn_global_load_lds((glb_u32_t*)src,
                                         (lds_u32_t*)(lds + (size_t)cid * 8), 16, 0, 0);
    }
}

__device__ __forceinline__ void gemm_core_db(const u16* __restrict__ Ab,
                                             const u16* __restrict__ Bb,
                                             u16* As, u16* Bs,   // each 2*8192 u16
                                             int tid, f32x4 acc[4][4])
{
    const int w = tid >> 6, l = tid & 63;
    const int wm = (w >> 1) * 64, wn = (w & 1) * 64;
    const int lr = l & 15, kq = l >> 4;

    stage128(Ab, 0, As, tid);
    stage128(Bb, 0, Bs, tid);

    for (int it = 0; it < DIM / 64; ++it) {
        const int cur = it & 1;
        u16* Ac = As + cur * 8192;
        u16* Bc = Bs + cur * 8192;
        __syncthreads();
        if (it + 1 < DIM / 64) {
            stage128(Ab, (it + 1) * 64, As + (cur ^ 1) * 8192, tid);
            stage128(Bb, (it + 1) * 64, Bs + (cur ^ 1) * 8192, tid);
        }
        #pragma unroll
        for (int ks = 0; ks < 2; ++ks) {
            s16x8 af[4], bfr[4];
            #pragma unroll
            for (int i = 0; i < 4; ++i)
                af[i]  = *(const s16x8*)(Ac + ks * 4096 + (wm + i * 16 + lr) * 32 + kq * 8);
            #pragma unroll
            for (int j = 0; j < 4; ++j)
                bfr[j] = *(const s16x8*)(Bc + ks * 4096 + (wn + j * 16 + lr) * 32 + kq * 8);
            #pragma unroll
            for (int i = 0; i < 4; ++i)
                #pragma unroll
                for (int j = 0; j < 4; ++j)
                    acc[i][j] = __builtin_amdgcn_mfma_f32_16x16x32_bf16(af[i], bfr[j], acc[i][j], 0, 0, 0);
        }
    }
}

// ---------------------------------------------------------------------------
// Double-buffered core B: tile 64x128, BK=64, 256 thr = 4 waves (2m x 2n),
// wave tile 32x64 (2x4 MFMAs per 32-k step). LDS: A 2x8 KB + B 2x16 KB =
// 48 KB -> grid 512 = 2 blocks/CU for MLP shapes.
// ---------------------------------------------------------------------------
__device__ __forceinline__ void gemm_core_db64(const u16* __restrict__ Ab,
                                               const u16* __restrict__ Bb,
                                               u16* As /*2*4096*/, u16* Bs /*2*8192*/,
                                               int tid, f32x4 acc[2][4])
{
    const int w = tid >> 6, l = tid & 63;
    const int wm = (w >> 1) * 32, wn = (w & 1) * 64;
    const int lr = l & 15, kq = l >> 4;

    // stage lambdas (A: 2 chunks/thread, B: 4 chunks/thread)
    auto stageA = [&](int k0, u16* lds) {
        #pragma unroll
        for (int j = 0; j < 2; ++j) {
            const int cid = j * 256 + tid;      // 0..511
            const int p = cid >> 8, r = (cid >> 2) & 63, cg = cid & 3;
            const u16* src = Ab + (size_t)r * DIM + k0 + p * 32 + cg * 8;
            __builtin_amdgcn_global_load_lds((glb_u32_t*)src,
                                             (lds_u32_t*)(lds + (size_t)cid * 8), 16, 0, 0);
        }
    };
    auto stageB = [&](int k0, u16* lds) {
        #pragma unroll
        for (int j = 0; j < 4; ++j) {
            const int cid = j * 256 + tid;      // 0..1023
            const int p = cid >> 9, r = (cid >> 2) & 127, cg = cid & 3;
            const u16* src = Bb + (size_t)r * DIM + k0 + p * 32 + cg * 8;
            __builtin_amdgcn_global_load_lds((glb_u32_t*)src,
                                             (lds_u32_t*)(lds + (size_t)cid * 8), 16, 0, 0);
        }
    };

    stageA(0, As);
    stageB(0, Bs);

    for (int it = 0; it < DIM / 64; ++it) {
        const int cur = it & 1;
        u16* Ac = As + cur * 4096;
        u16* Bc = Bs + cur * 8192;
        __syncthreads();
        if (it + 1 < DIM / 64) {
            stageA((it + 1) * 64, As + (cur ^ 1) * 4096);
            stageB((it + 1) * 64, Bs + (cur ^ 1) * 8192);
        }
        #pragma unroll
        for (int ks = 0; ks < 2; ++ks) {
            s16x8 af[2], bfr[4];
            #pragma unroll
            for (int i = 0; i < 2; ++i)
                af[i]  = *(const s16x8*)(Ac + ks * 2048 + (wm + i * 16 + lr) * 32 + kq * 8);
            #pragma unroll
            for (int j = 0; j < 4; ++j)
                bfr[j] = *(const s16x8*)(Bc + ks * 4096 + (wn + j * 16 + lr) * 32 + kq * 8);
            #pragma unroll
            for (int i = 0; i < 2; ++i)
                #pragma unroll
                for (int j = 0; j < 4; ++j)
                    acc[i][j] = __builtin_amdgcn_mfma_f32_16x16x32_bf16(af[i], bfr[j], acc[i][j], 0, 0, 0);
        }
    }
}

// ---------------------------------------------------------------------------
// Fused QKV projection: grid (24, 32), 256 threads, db-128 core.
// ---------------------------------------------------------------------------
__global__ __launch_bounds__(256)
void qkv_gemm(const u16* __restrict__ xb,
              const u16* __restrict__ Wq, const u16* __restrict__ Wk, const u16* __restrict__ Wv,
              const float* __restrict__ bq, const float* __restrict__ bk, const float* __restrict__ bv,
              u16* __restrict__ qo, u16* __restrict__ ko, u16* __restrict__ vo)
{
    __shared__ u16 As[2 * 8192];
    __shared__ u16 Bs[2 * 8192];
    const int tid = threadIdx.x;
    const int sel = blockIdx.x >> 3;
    const int n0  = (blockIdx.x & 7) * 128;
    const int m0  = blockIdx.y * 128;
    const u16*   B    = (sel == 0) ? Wq : (sel == 1) ? Wk : Wv;
    const float* bias = (sel == 0) ? bq : (sel == 1) ? bk : bv;
    u16*         C    = (sel == 0) ? qo : (sel == 1) ? ko : vo;
    const float scale = (sel == 0) ? 0.125f : 1.0f;

    f32x4 acc[4][4];
    #pragma unroll
    for (int i = 0; i < 4; ++i)
        #pragma unroll
        for (int j = 0; j < 4; ++j) acc[i][j] = (f32x4){0.f, 0.f, 0.f, 0.f};

    gemm_core_db(xb + (size_t)m0 * DIM, B + (size_t)n0 * DIM, As, Bs, tid, acc);

    const int w = tid >> 6, l = tid & 63;
    const int wm = (w >> 1) * 64, wn = (w & 1) * 64;
    const int er = l >> 4, ec = l & 15;
    #pragma unroll
    for (int j = 0; j < 4; ++j) {
        const int n = n0 + wn + j * 16 + ec;
        const float bb = bias[n];
        #pragma unroll
        for (int i = 0; i < 4; ++i)
            #pragma unroll
            for (int r = 0; r < 4; ++r) {
                const int m = m0 + wm + i * 16 + er * 4 + r;
                C[(size_t)m * DIM + n] = f2bf((acc[i][j][r] + bb) * scale);
            }
    }
}

// ---------------------------------------------------------------------------
// MLP GEMMs: 256 threads, grid (8, 64) = 512 blocks (2/CU), tile 64x128,
// db-64 core. mode 1: gelu -> bf16.  mode 2: +bias +x +attn -> fp32.
// ---------------------------------------------------------------------------
__global__ __launch_bounds__(256)
void gemm_bf16(const u16* __restrict__ A, const u16* __restrict__ B,
               const float* __restrict__ bias,
               u16* __restrict__ Cb, float* __restrict__ Cf,
               const float* __restrict__ rx, const u16* __restrict__ rattn,
               int mode)
{
    __shared__ u16 As[2 * 4096];
    __shared__ u16 Bs[2 * 8192];
    const int tid = threadIdx.x;
    const int n0 = blockIdx.x * 128, m0 = blockIdx.y * 64;

    f32x4 acc[2][4];
    #pragma unroll
    for (int i = 0; i < 2; ++i)
        #pragma unroll
        for (int j = 0; j < 4; ++j) acc[i][j] = (f32x4){0.f, 0.f, 0.f, 0.f};

    gemm_core_db64(A + (size_t)m0 * DIM, B + (size_t)n0 * DIM, As, Bs, tid, acc);

    const int w = tid >> 6, l = tid & 63;
    const int wm = (w >> 1) * 32, wn = (w & 1) * 64;
    const int er = l >> 4, ec = l & 15;
    #pragma unroll
    for (int j = 0; j < 4; ++j) {
        const int n = n0 + wn + j * 16 + ec;
        const float bb = bias[n];
        #pragma unroll
        for (int i = 0; i < 2; ++i)
            #pragma unroll
            for (int r = 0; r < 4; ++r) {
                const int m = m0 + wm + i * 16 + er * 4 + r;
                const size_t idx = (size_t)m * DIM + n;
                float v = acc[i][j][r] + bb;
                if (mode == 1) {
                    v = 0.5f * v * (1.0f + erff(v * 0.70710678118654752f));
                    Cb[idx] = f2bf(v);
                } else {
                    Cf[idx] = v + rx[idx] + bf2f(rattn[idx]);
                }
            }
    }
}

// ---------------------------------------------------------------------------
// ktv via MFMA, no atomics. grid 256 = 32 (b,h) x 8 s-splits, 256 threads.
// ---------------------------------------------------------------------------
__global__ __launch_bounds__(256)
void ktv_mfma(const u16* __restrict__ Kb, const u16* __restrict__ Vb,
              float* __restrict__ part)
{
    __shared__ u16 Kt[64 * 264];
    __shared__ u16 Vt[64 * 264];
    const int tid = threadIdx.x;
    const int bh = blockIdx.x & 31;
    const int sp = blockIdx.x >> 5;
    const int b = bh >> 4, h = bh & 15;
    const size_t base = (size_t)b * SEQ * DIM + (size_t)h * HDIM + (size_t)sp * 256 * DIM;

    const int dg = (tid & 15) * 4;
    #pragma unroll
    for (int pass = 0; pass < 16; ++pass) {
        const int s = (tid >> 4) + 16 * pass;
        ushort4 kv = *(const ushort4*)(Kb + base + (size_t)s * DIM + dg);
        ushort4 vv = *(const ushort4*)(Vb + base + (size_t)s * DIM + dg);
        Kt[(dg + 0) * 264 + s] = kv.x; Kt[(dg + 1) * 264 + s] = kv.y;
        Kt[(dg + 2) * 264 + s] = kv.z; Kt[(dg + 3) * 264 + s] = kv.w;
        Vt[(dg + 0) * 264 + s] = vv.x; Vt[(dg + 1) * 264 + s] = vv.y;
        Vt[(dg + 2) * 264 + s] = vv.z; Vt[(dg + 3) * 264 + s] = vv.w;
    }
    __syncthreads();

    const int w = tid >> 6, l = tid & 63;
    const int lr = l & 15, kq = l >> 4;
    f32x4 acc[4];
    #pragma unroll
    for (int j = 0; j < 4; ++j) acc[j] = (f32x4){0.f, 0.f, 0.f, 0.f};

    for (int k0 = 0; k0 < 256; k0 += 32) {
        s16x8 af = *(const s16x8*)(Kt + (w * 16 + lr) * 264 + k0 + kq * 8);
        #pragma unroll
        for (int j = 0; j < 4; ++j) {
            s16x8 bf = *(const s16x8*)(Vt + (j * 16 + lr) * 264 + k0 + kq * 8);
            acc[j] = __builtin_amdgcn_mfma_f32_16x16x32_bf16(af, bf, acc[j], 0, 0, 0);
        }
    }

    float* dst = part + ((size_t)sp * 32 + bh) * (HDIM * HDIM);
    const int er = l >> 4, ec = l & 15;
    #pragma unroll
    for (int j = 0; j < 4; ++j)
        #pragma unroll
        for (int r = 0; r < 4; ++r)
            dst[(w * 16 + er * 4 + r) * HDIM + j * 16 + ec] = acc[j][r];
}

// ---------------------------------------------------------------------------
// attn = Q @ KtV (block-diag per head), fused partial-reduction.
// ---------------------------------------------------------------------------
__global__ __launch_bounds__(256)
void qktv_kernel(const u16* __restrict__ Qb, const float* __restrict__ part,
                 u16* __restrict__ attnb)
{
    __shared__ float KV[HDIM * HDIM];
    __shared__ u16 Qs[128 * 68];
    const int tid = threadIdx.x;
    const int h  = blockIdx.x;
    const int mt = blockIdx.y;
    const int row0 = mt * 128;
    const int b = row0 >> 11;
    const int bh = b * NHEAD + h;

    for (int i = tid; i < HDIM * HDIM; i += 256) {
        float s = 0.f;
        #pragma unroll
        for (int sp = 0; sp < NSPLIT; ++sp)
            s += part[((size_t)sp * 32 + bh) * (HDIM * HDIM) + i];
        KV[i] = s;
    }
    const int dg = (tid & 15) * 4;
    #pragma unroll
    for (int pass = 0; pass < 8; ++pass) {
        const int r = (tid >> 4) + 16 * pass;
        ushort4 q = *(const ushort4*)(Qb + (size_t)(row0 + r) * DIM + h * HDIM + dg);
        *(ushort4*)(Qs + r * 68 + dg) = q;
    }
    __syncthreads();

    const int tr = tid >> 3, tc = tid & 7;
    const int r0 = tr * 4, c0 = tc * 8;
    float acc[4][8] = {};
    for (int d = 0; d < HDIM; ++d) {
        float4 ka  = *(const float4*)&KV[d * HDIM + c0];
        float4 kb2 = *(const float4*)&KV[d * HDIM + c0 + 4];
        const float* k8a = (const float*)&ka;
        const float* k8b = (const float*)&kb2;
        float qv[4];
        #pragma unroll
        for (int i = 0; i < 4; ++i) qv[i] = bf2f(Qs[(r0 + i) * 68 + d]);
        #pragma unroll
        for (int i = 0; i < 4; ++i)
            #pragma unroll
            for (int j = 0; j < 4; ++j) {
                acc[i][j]     += qv[i] * k8a[j];
                acc[i][j + 4] += qv[i] * k8b[j];
            }
    }
    #pragma unroll
    for (int i = 0; i < 4; ++i) {
        u16* dst = attnb + (size_t)(row0 + r0 + i) * DIM + h * HDIM + c0;
        ushort4 o0 = { f2bf(acc[i][0]), f2bf(acc[i][1]), f2bf(acc[i][2]), f2bf(acc[i][3]) };
        ushort4 o1 = { f2bf(acc[i][4]), f2bf(acc[i][5]), f2bf(acc[i][6]), f2bf(acc[i][7]) };
        *(ushort4*)(dst)     = o0;
        *(ushort4*)(dst + 4) = o1;
    }
}

// ---------------------------------------------------------------------------
extern "C" void kernel_launch(void* const* d_in, const int* in_sizes, int n_in,
                              void* d_out, int out_size, void* d_ws, size_t ws_size,
                              hipStream_t stream)
{
    const float* x  = (const float*)d_in[0];
    const float* Wq = (const float*)d_in[1];
    const float* bq = (const float*)d_in[2];
    const float* Wk = (const float*)d_in[3];
    const float* bk = (const float*)d_in[4];
    const float* Wv = (const float*)d_in[5];
    const float* bv = (const float*)d_in[6];
    const float* W1 = (const float*)d_in[7];
    const float* b1 = (const float*)d_in[8];
    const float* W2 = (const float*)d_in[9];
    const float* b2 = (const float*)d_in[10];
    float* out = (float*)d_out;

    char* ws = (char*)d_ws;
    const size_t MB = 1u << 20;
    u16* xb   = (u16*)(ws);              //  8 MB
    u16* Wqb  = (u16*)(ws +  8 * MB);    //  2 MB each
    u16* Wkb  = (u16*)(ws + 10 * MB);
    u16* Wvb  = (u16*)(ws + 12 * MB);
    u16* W1b  = (u16*)(ws + 14 * MB);
    u16* W2b  = (u16*)(ws + 16 * MB);
    u16* qb   = (u16*)(ws + 18 * MB);    //  8 MB
    u16* kb   = (u16*)(ws + 26 * MB);    //  8 MB
    u16* vb   = (u16*)(ws + 34 * MB);    //  8 MB
    float* part = (float*)(ws + 42 * MB);//  4 MB
    u16* attnb = kb;
    u16* h1b   = vb;

    pack_all<<<4096 + 5 * 1024, 256, 0, stream>>>(x, Wq, Wk, Wv, W1, W2,
                                                  xb, Wqb, Wkb, Wvb, W1b, W2b);

    qkv_gemm<<<dim3(24, 32), 256, 0, stream>>>(xb, Wqb, Wkb, Wvb, bq, bk, bv, qb, kb, vb);

    ktv_mfma<<<NSPLIT * 32, 256, 0, stream>>>(kb, vb, part);
    qktv_kernel<<<dim3(NHEAD, MROWS / 128), 256, 0, stream>>>(qb, part, attnb);

    gemm_bf16<<<dim3(8, 64), 256, 0, stream>>>(attnb, W1b, b1, h1b, nullptr, nullptr, nullptr, 1);
    gemm_bf16<<<dim3(8, 64), 256, 0, stream>>>(h1b, W2b, b2, nullptr, out, x, attnb, 2);
}

// Round 7
// 203.871 us; speedup vs baseline: 1.0824x; 1.0824x over previous
//
#include <hip/hip_runtime.h>
#include <math.h>

#define DIM    1024
#define BATCH  2
#define SEQ    2048
#define NHEAD  16
#define HDIM   64
#define MROWS  (BATCH*SEQ)   // 4096
#define NSPLIT 8             // ktv S-splits

typedef unsigned short u16;
typedef __attribute__((ext_vector_type(8))) short  s16x8;   // 8 bf16 = 4 VGPRs
typedef __attribute__((ext_vector_type(4))) float  f32x4;

typedef __attribute__((address_space(3))) unsigned int       lds_u32_t;
typedef const __attribute__((address_space(1))) unsigned int glb_u32_t;

__device__ __forceinline__ float bf2f(u16 h) {
    unsigned u = ((unsigned)h) << 16; float f; __builtin_memcpy(&f, &u, 4); return f;
}
__device__ __forceinline__ u16 f2bf(float f) {
    unsigned u; __builtin_memcpy(&u, &f, 4);
    u += 0x7FFFu + ((u >> 16) & 1u);           // round-to-nearest-even
    return (u16)(u >> 16);
}

// ---------------------------------------------------------------------------
// Fused fp32->bf16 pack for x + 5 weights. One launch.
// ---------------------------------------------------------------------------
__global__ __launch_bounds__(256)
void pack_all(const float* __restrict__ x,
              const float* __restrict__ Wq, const float* __restrict__ Wk,
              const float* __restrict__ Wv, const float* __restrict__ W1,
              const float* __restrict__ W2,
              u16* __restrict__ xb, u16* __restrict__ Wqb, u16* __restrict__ Wkb,
              u16* __restrict__ Wvb, u16* __restrict__ W1b, u16* __restrict__ W2b)
{
    const int bid = blockIdx.x;
    const float* src; u16* dst; int i;
    if (bid < 4096) { src = x; dst = xb; i = bid * 256 + threadIdx.x; }
    else {
        const int w = (bid - 4096) >> 10;
        const int lb = (bid - 4096) & 1023;
        src = (w == 0) ? Wq : (w == 1) ? Wk : (w == 2) ? Wv : (w == 3) ? W1 : W2;
        dst = (w == 0) ? Wqb : (w == 1) ? Wkb : (w == 2) ? Wvb : (w == 3) ? W1b : W2b;
        i = lb * 256 + threadIdx.x;
    }
    float4 v = ((const float4*)src)[i];
    ushort4 o = { f2bf(v.x), f2bf(v.y), f2bf(v.z), f2bf(v.w) };
    ((ushort4*)dst)[i] = o;
}

// ---------------------------------------------------------------------------
// m97-exact MFMA GEMM core: 256 threads = 4 waves (2x2), block tile 128x128,
// wave tile 64x64 via 4x4 of 16x16x32_bf16. BK=32, LDS 8 KB/operand (16 KB
// total) -> 164 VGPR, ~3 blocks/CU. global_load_lds width=16 staging.
// ---------------------------------------------------------------------------
__device__ __forceinline__ void stage_tile(const u16* __restrict__ gbase, int k0,
                                           u16* lds, int tid)
{
    #pragma unroll
    for (int p = 0; p < 2; ++p) {
        int e   = p * 256 + tid;           // 0..511, 16B chunk id
        int row = e >> 2;                  // 0..127
        int cg  = e & 3;                   // colgroup of 8 bf16
        const u16* src = gbase + (size_t)row * DIM + k0 + cg * 8;
        __builtin_amdgcn_global_load_lds((glb_u32_t*)src, (lds_u32_t*)(lds + e * 8), 16, 0, 0);
    }
}

__device__ __forceinline__ void gemm_core_m97(const u16* __restrict__ Ab,
                                              const u16* __restrict__ Bb,
                                              u16* As, u16* Bs, int tid,
                                              f32x4 acc[4][4])
{
    const int w = tid >> 6, l = tid & 63;
    const int wm = (w >> 1) * 64, wn = (w & 1) * 64;
    const int lr = l & 15, kq = l >> 4;

    for (int k0 = 0; k0 < DIM; k0 += 32) {
        stage_tile(Ab, k0, As, tid);
        stage_tile(Bb, k0, Bs, tid);
        __syncthreads();
        s16x8 af[4], bfr[4];
        #pragma unroll
        for (int i = 0; i < 4; ++i)
            af[i]  = *(const s16x8*)(As + (wm + i * 16 + lr) * 32 + kq * 8);
        #pragma unroll
        for (int j = 0; j < 4; ++j)
            bfr[j] = *(const s16x8*)(Bs + (wn + j * 16 + lr) * 32 + kq * 8);
        #pragma unroll
        for (int i = 0; i < 4; ++i)
            #pragma unroll
            for (int j = 0; j < 4; ++j)
                acc[i][j] = __builtin_amdgcn_mfma_f32_16x16x32_bf16(af[i], bfr[j], acc[i][j], 0, 0, 0);
        __syncthreads();
    }
}

// ---------------------------------------------------------------------------
// 256-thread MLP core: tile M=64 x N=128, BK=32, 4 waves (2m x 2n), wave tile
// 32x64 = 2x4 MFMAs. LDS 12 KB. (round-5 proven)
// ---------------------------------------------------------------------------
__device__ __forceinline__ void gemm_core4_m64(const u16* __restrict__ Ab,
                                               const u16* __restrict__ Bb,
                                               u16* As /*64x32*/, u16* Bs /*128x32*/,
                                               int tid, f32x4 acc[2][4])
{
    const int w  = tid >> 6, l = tid & 63;
    const int wm = (w >> 1) * 32, wn = (w & 1) * 64;
    const int lr = l & 15, kq = l >> 4;
    const int ar = tid >> 2, acg = tid & 3;     // A: 1 chunk/thread

    for (int k0 = 0; k0 < DIM; k0 += 32) {
        const u16* srcA = Ab + (size_t)ar * DIM + k0 + acg * 8;
        __builtin_amdgcn_global_load_lds((glb_u32_t*)srcA, (lds_u32_t*)(As + tid * 8), 16, 0, 0);
        #pragma unroll
        for (int j = 0; j < 2; ++j) {           // B: 2 chunks/thread
            const int cid = j * 256 + tid;
            const int br = cid >> 2, bcg = cid & 3;
            const u16* srcB = Bb + (size_t)br * DIM + k0 + bcg * 8;
            __builtin_amdgcn_global_load_lds((glb_u32_t*)srcB, (lds_u32_t*)(Bs + cid * 8), 16, 0, 0);
        }
        __syncthreads();
        s16x8 af[2], bfr[4];
        #pragma unroll
        for (int i = 0; i < 2; ++i)
            af[i]  = *(const s16x8*)(As + (wm + i * 16 + lr) * 32 + kq * 8);
        #pragma unroll
        for (int j = 0; j < 4; ++j)
            bfr[j] = *(const s16x8*)(Bs + (wn + j * 16 + lr) * 32 + kq * 8);
        #pragma unroll
        for (int i = 0; i < 2; ++i)
            #pragma unroll
            for (int j = 0; j < 4; ++j)
                acc[i][j] = __builtin_amdgcn_mfma_f32_16x16x32_bf16(af[i], bfr[j], acc[i][j], 0, 0, 0);
        __syncthreads();
    }
}

// ---------------------------------------------------------------------------
// Fused QKV projection: grid (32 m-tiles, 24 sel*n-tiles), 256 threads.
// Grid swizzle: consecutive blocks (x-fastest) share the SAME weight tile and
// vary m -> per-XCD weight working set ~0.75 MB (fits 4 MB L2).
// ---------------------------------------------------------------------------
__global__ __launch_bounds__(256)
void qkv_gemm(const u16* __restrict__ xb,
              const u16* __restrict__ Wq, const u16* __restrict__ Wk, const u16* __restrict__ Wv,
              const float* __restrict__ bq, const float* __restrict__ bk, const float* __restrict__ bv,
              u16* __restrict__ qo, u16* __restrict__ ko, u16* __restrict__ vo)
{
    __shared__ u16 As[128 * 32];
    __shared__ u16 Bs[128 * 32];
    const int tid = threadIdx.x;
    const int m0  = blockIdx.x * 128;
    const int sel = blockIdx.y >> 3;
    const int n0  = (blockIdx.y & 7) * 128;
    const u16*   B    = (sel == 0) ? Wq : (sel == 1) ? Wk : Wv;
    const float* bias = (sel == 0) ? bq : (sel == 1) ? bk : bv;
    u16*         C    = (sel == 0) ? qo : (sel == 1) ? ko : vo;
    const float scale = (sel == 0) ? 0.125f : 1.0f;

    f32x4 acc[4][4];
    #pragma unroll
    for (int i = 0; i < 4; ++i)
        #pragma unroll
        for (int j = 0; j < 4; ++j) acc[i][j] = (f32x4){0.f, 0.f, 0.f, 0.f};

    gemm_core_m97(xb + (size_t)m0 * DIM, B + (size_t)n0 * DIM, As, Bs, tid, acc);

    const int w = tid >> 6, l = tid & 63;
    const int wm = (w >> 1) * 64, wn = (w & 1) * 64;
    const int er = l >> 4, ec = l & 15;
    #pragma unroll
    for (int j = 0; j < 4; ++j) {
        const int n = n0 + wn + j * 16 + ec;
        const float bb = bias[n];
        #pragma unroll
        for (int i = 0; i < 4; ++i)
            #pragma unroll
            for (int r = 0; r < 4; ++r) {
                const int m = m0 + wm + i * 16 + er * 4 + r;
                C[(size_t)m * DIM + n] = f2bf((acc[i][j][r] + bb) * scale);
            }
    }
}

// ---------------------------------------------------------------------------
// MLP GEMMs: 256 threads, grid (64 m-tiles, 8 n-tiles) = 512 blocks (2/CU),
// tile 64x128. Consecutive blocks share one weight tile (XCD L2 locality).
// mode 1: gelu -> bf16.   mode 2: +bias +x +attn -> fp32.
// ---------------------------------------------------------------------------
__global__ __launch_bounds__(256)
void gemm_bf16(const u16* __restrict__ A, const u16* __restrict__ B,
               const float* __restrict__ bias,
               u16* __restrict__ Cb, float* __restrict__ Cf,
               const float* __restrict__ rx, const u16* __restrict__ rattn,
               int mode)
{
    __shared__ u16 As[64 * 32];
    __shared__ u16 Bs[128 * 32];
    const int tid = threadIdx.x;
    const int m0 = blockIdx.x * 64, n0 = blockIdx.y * 128;

    f32x4 acc[2][4];
    #pragma unroll
    for (int i = 0; i < 2; ++i)
        #pragma unroll
        for (int j = 0; j < 4; ++j) acc[i][j] = (f32x4){0.f, 0.f, 0.f, 0.f};

    gemm_core4_m64(A + (size_t)m0 * DIM, B + (size_t)n0 * DIM, As, Bs, tid, acc);

    const int w = tid >> 6, l = tid & 63;
    const int wm = (w >> 1) * 32, wn = (w & 1) * 64;
    const int er = l >> 4, ec = l & 15;
    #pragma unroll
    for (int j = 0; j < 4; ++j) {
        const int n = n0 + wn + j * 16 + ec;
        const float bb = bias[n];
        #pragma unroll
        for (int i = 0; i < 2; ++i)
            #pragma unroll
            for (int r = 0; r < 4; ++r) {
                const int m = m0 + wm + i * 16 + er * 4 + r;
                const size_t idx = (size_t)m * DIM + n;
                float v = acc[i][j][r] + bb;
                if (mode == 1) {
                    v = 0.5f * v * (1.0f + erff(v * 0.70710678118654752f));
                    Cb[idx] = f2bf(v);
                } else {
                    Cf[idx] = v + rx[idx] + bf2f(rattn[idx]);
                }
            }
    }
}

// ---------------------------------------------------------------------------
// ktv via MFMA, no atomics. grid 256 = 32 (b,h) x 8 s-splits, 256 threads.
// ---------------------------------------------------------------------------
__global__ __launch_bounds__(256)
void ktv_mfma(const u16* __restrict__ Kb, const u16* __restrict__ Vb,
              float* __restrict__ part)
{
    __shared__ u16 Kt[64 * 264];
    __shared__ u16 Vt[64 * 264];
    const int tid = threadIdx.x;
    const int bh = blockIdx.x & 31;
    const int sp = blockIdx.x >> 5;
    const int b = bh >> 4, h = bh & 15;
    const size_t base = (size_t)b * SEQ * DIM + (size_t)h * HDIM + (size_t)sp * 256 * DIM;

    const int dg = (tid & 15) * 4;
    #pragma unroll
    for (int pass = 0; pass < 16; ++pass) {
        const int s = (tid >> 4) + 16 * pass;
        ushort4 kv = *(const ushort4*)(Kb + base + (size_t)s * DIM + dg);
        ushort4 vv = *(const ushort4*)(Vb + base + (size_t)s * DIM + dg);
        Kt[(dg + 0) * 264 + s] = kv.x; Kt[(dg + 1) * 264 + s] = kv.y;
        Kt[(dg + 2) * 264 + s] = kv.z; Kt[(dg + 3) * 264 + s] = kv.w;
        Vt[(dg + 0) * 264 + s] = vv.x; Vt[(dg + 1) * 264 + s] = vv.y;
        Vt[(dg + 2) * 264 + s] = vv.z; Vt[(dg + 3) * 264 + s] = vv.w;
    }
    __syncthreads();

    const int w = tid >> 6, l = tid & 63;
    const int lr = l & 15, kq = l >> 4;
    f32x4 acc[4];
    #pragma unroll
    for (int j = 0; j < 4; ++j) acc[j] = (f32x4){0.f, 0.f, 0.f, 0.f};

    for (int k0 = 0; k0 < 256; k0 += 32) {
        s16x8 af = *(const s16x8*)(Kt + (w * 16 + lr) * 264 + k0 + kq * 8);
        #pragma unroll
        for (int j = 0; j < 4; ++j) {
            s16x8 bf = *(const s16x8*)(Vt + (j * 16 + lr) * 264 + k0 + kq * 8);
            acc[j] = __builtin_amdgcn_mfma_f32_16x16x32_bf16(af, bf, acc[j], 0, 0, 0);
        }
    }

    float* dst = part + ((size_t)sp * 32 + bh) * (HDIM * HDIM);
    const int er = l >> 4, ec = l & 15;
    #pragma unroll
    for (int j = 0; j < 4; ++j)
        #pragma unroll
        for (int r = 0; r < 4; ++r)
            dst[(w * 16 + er * 4 + r) * HDIM + j * 16 + ec] = acc[j][r];
}

// ---------------------------------------------------------------------------
// attn = Q @ KtV (block-diag per head), fused partial-reduction.
// ---------------------------------------------------------------------------
__global__ __launch_bounds__(256)
void qktv_kernel(const u16* __restrict__ Qb, const float* __restrict__ part,
                 u16* __restrict__ attnb)
{
    __shared__ float KV[HDIM * HDIM];
    __shared__ u16 Qs[128 * 68];
    const int tid = threadIdx.x;
    const int h  = blockIdx.x;
    const int mt = blockIdx.y;
    const int row0 = mt * 128;
    const int b = row0 >> 11;
    const int bh = b * NHEAD + h;

    for (int i = tid; i < HDIM * HDIM; i += 256) {
        float s = 0.f;
        #pragma unroll
        for (int sp = 0; sp < NSPLIT; ++sp)
            s += part[((size_t)sp * 32 + bh) * (HDIM * HDIM) + i];
        KV[i] = s;
    }
    const int dg = (tid & 15) * 4;
    #pragma unroll
    for (int pass = 0; pass < 8; ++pass) {
        const int r = (tid >> 4) + 16 * pass;
        ushort4 q = *(const ushort4*)(Qb + (size_t)(row0 + r) * DIM + h * HDIM + dg);
        *(ushort4*)(Qs + r * 68 + dg) = q;
    }
    __syncthreads();

    const int tr = tid >> 3, tc = tid & 7;
    const int r0 = tr * 4, c0 = tc * 8;
    float acc[4][8] = {};
    for (int d = 0; d < HDIM; ++d) {
        float4 ka  = *(const float4*)&KV[d * HDIM + c0];
        float4 kb2 = *(const float4*)&KV[d * HDIM + c0 + 4];
        const float* k8a = (const float*)&ka;
        const float* k8b = (const float*)&kb2;
        float qv[4];
        #pragma unroll
        for (int i = 0; i < 4; ++i) qv[i] = bf2f(Qs[(r0 + i) * 68 + d]);
        #pragma unroll
        for (int i = 0; i < 4; ++i)
            #pragma unroll
            for (int j = 0; j < 4; ++j) {
                acc[i][j]     += qv[i] * k8a[j];
                acc[i][j + 4] += qv[i] * k8b[j];
            }
    }
    #pragma unroll
    for (int i = 0; i < 4; ++i) {
        u16* dst = attnb + (size_t)(row0 + r0 + i) * DIM + h * HDIM + c0;
        ushort4 o0 = { f2bf(acc[i][0]), f2bf(acc[i][1]), f2bf(acc[i][2]), f2bf(acc[i][3]) };
        ushort4 o1 = { f2bf(acc[i][4]), f2bf(acc[i][5]), f2bf(acc[i][6]), f2bf(acc[i][7]) };
        *(ushort4*)(dst)     = o0;
        *(ushort4*)(dst + 4) = o1;
    }
}

// ---------------------------------------------------------------------------
extern "C" void kernel_launch(void* const* d_in, const int* in_sizes, int n_in,
                              void* d_out, int out_size, void* d_ws, size_t ws_size,
                              hipStream_t stream)
{
    const float* x  = (const float*)d_in[0];
    const float* Wq = (const float*)d_in[1];
    const float* bq = (const float*)d_in[2];
    const float* Wk = (const float*)d_in[3];
    const float* bk = (const float*)d_in[4];
    const float* Wv = (const float*)d_in[5];
    const float* bv = (const float*)d_in[6];
    const float* W1 = (const float*)d_in[7];
    const float* b1 = (const float*)d_in[8];
    const float* W2 = (const float*)d_in[9];
    const float* b2 = (const float*)d_in[10];
    float* out = (float*)d_out;

    char* ws = (char*)d_ws;
    const size_t MB = 1u << 20;
    u16* xb   = (u16*)(ws);              //  8 MB
    u16* Wqb  = (u16*)(ws +  8 * MB);    //  2 MB each
    u16* Wkb  = (u16*)(ws + 10 * MB);
    u16* Wvb  = (u16*)(ws + 12 * MB);
    u16* W1b  = (u16*)(ws + 14 * MB);
    u16* W2b  = (u16*)(ws + 16 * MB);
    u16* qb   = (u16*)(ws + 18 * MB);    //  8 MB
    u16* kb   = (u16*)(ws + 26 * MB);    //  8 MB
    u16* vb   = (u16*)(ws + 34 * MB);    //  8 MB
    float* part = (float*)(ws + 42 * MB);//  4 MB
    u16* attnb = kb;
    u16* h1b   = vb;

    pack_all<<<4096 + 5 * 1024, 256, 0, stream>>>(x, Wq, Wk, Wv, W1, W2,
                                                  xb, Wqb, Wkb, Wvb, W1b, W2b);

    // m97 core, XCD-swizzled grid: x = m-tile, y = sel*8 + n-tile
    qkv_gemm<<<dim3(32, 24), 256, 0, stream>>>(xb, Wqb, Wkb, Wvb, bq, bk, bv, qb, kb, vb);

    ktv_mfma<<<NSPLIT * 32, 256, 0, stream>>>(kb, vb, part);
    qktv_kernel<<<dim3(NHEAD, MROWS / 128), 256, 0, stream>>>(qb, part, attnb);

    // x = m-tile (64), y = n-tile (8)
    gemm_bf16<<<dim3(64, 8), 256, 0, stream>>>(attnb, W1b, b1, h1b, nullptr, nullptr, nullptr, 1);
    gemm_bf16<<<dim3(64, 8), 256, 0, stream>>>(h1b, W2b, b2, nullptr, out, x, attnb, 2);
}

// Round 8
// 203.713 us; speedup vs baseline: 1.0833x; 1.0008x over previous
//
#include <hip/hip_runtime.h>
#include <math.h>

#define DIM    1024
#define BATCH  2
#define SEQ    2048
#define NHEAD  16
#define HDIM   64
#define MROWS  (BATCH*SEQ)   // 4096
#define NSPLIT 8             // ktv S-splits

typedef unsigned short u16;
typedef __attribute__((ext_vector_type(8))) short  s16x8;   // 8 bf16 = 4 VGPRs
typedef __attribute__((ext_vector_type(4))) float  f32x4;

__device__ __forceinline__ float bf2f(u16 h) {
    unsigned u = ((unsigned)h) << 16; float f; __builtin_memcpy(&f, &u, 4); return f;
}
__device__ __forceinline__ u16 f2bf(float f) {
    unsigned u; __builtin_memcpy(&u, &f, 4);
    u += 0x7FFFu + ((u >> 16) & 1u);           // round-to-nearest-even
    return (u16)(u >> 16);
}

// ---------------------------------------------------------------------------
// Fused fp32->bf16 pack for x + 5 weights. One launch.
// ---------------------------------------------------------------------------
__global__ __launch_bounds__(256)
void pack_all(const float* __restrict__ x,
              const float* __restrict__ Wq, const float* __restrict__ Wk,
              const float* __restrict__ Wv, const float* __restrict__ W1,
              const float* __restrict__ W2,
              u16* __restrict__ xb, u16* __restrict__ Wqb, u16* __restrict__ Wkb,
              u16* __restrict__ Wvb, u16* __restrict__ W1b, u16* __restrict__ W2b)
{
    const int bid = blockIdx.x;
    const float* src; u16* dst; int i;
    if (bid < 4096) { src = x; dst = xb; i = bid * 256 + threadIdx.x; }
    else {
        const int w = (bid - 4096) >> 10;
        const int lb = (bid - 4096) & 1023;
        src = (w == 0) ? Wq : (w == 1) ? Wk : (w == 2) ? Wv : (w == 3) ? W1 : W2;
        dst = (w == 0) ? Wqb : (w == 1) ? Wkb : (w == 2) ? Wvb : (w == 3) ? W1b : W2b;
        i = lb * 256 + threadIdx.x;
    }
    float4 v = ((const float4*)src)[i];
    ushort4 o = { f2bf(v.x), f2bf(v.y), f2bf(v.z), f2bf(v.w) };
    ((ushort4*)dst)[i] = o;
}

// ---------------------------------------------------------------------------
// Register-staged pipelined GEMM core, tile 128x128, BK=32, 256 thr = 4 waves
// (2x2), wave tile 64x64 (4x4 MFMAs). Double-buffered LDS (32 KB), ONE
// barrier/iter. Order: barrier -> issue loads(k+1) -> compute(cur) ->
// ds_write(next). The ds_write's vmcnt wait lands AFTER compute, so the
// barrier's vmcnt(0) drain is already satisfied (loads hidden under compute).
// ---------------------------------------------------------------------------
__device__ __forceinline__ void gemm_core_pf128(const u16* __restrict__ Ab,
                                                const u16* __restrict__ Bb,
                                                u16* As, u16* Bs,  // each 2*4096 u16
                                                int tid, f32x4 acc[4][4])
{
    const int w = tid >> 6, l = tid & 63;
    const int wm = (w >> 1) * 64, wn = (w & 1) * 64;
    const int lr = l & 15, kq = l >> 4;
    const int row = tid >> 2, cg8 = (tid & 3) * 8;

    const u16* a0 = Ab + (size_t)row * DIM + cg8;
    const u16* a1 = Ab + (size_t)(64 + row) * DIM + cg8;
    const u16* b0 = Bb + (size_t)row * DIM + cg8;
    const u16* b1 = Bb + (size_t)(64 + row) * DIM + cg8;

    uint4 pa0 = *(const uint4*)a0, pa1 = *(const uint4*)a1;
    uint4 pb0 = *(const uint4*)b0, pb1 = *(const uint4*)b1;
    *(uint4*)(As + tid * 8) = pa0;  *(uint4*)(As + 2048 + tid * 8) = pa1;
    *(uint4*)(Bs + tid * 8) = pb0;  *(uint4*)(Bs + 2048 + tid * 8) = pb1;

    const int NIT = DIM / 32;
    for (int it = 0; it < NIT; ++it) {
        u16* Ac = As + (it & 1) * 4096;
        u16* Bc = Bs + (it & 1) * 4096;
        __syncthreads();                       // buf[cur] visible
        if (it + 1 < NIT) {                    // issue next-tile loads
            const int k = (it + 1) * 32;
            pa0 = *(const uint4*)(a0 + k); pa1 = *(const uint4*)(a1 + k);
            pb0 = *(const uint4*)(b0 + k); pb1 = *(const uint4*)(b1 + k);
        }
        s16x8 af[4], bfr[4];
        #pragma unroll
        for (int i = 0; i < 4; ++i)
            af[i]  = *(const s16x8*)(Ac + (wm + i * 16 + lr) * 32 + kq * 8);
        #pragma unroll
        for (int j = 0; j < 4; ++j)
            bfr[j] = *(const s16x8*)(Bc + (wn + j * 16 + lr) * 32 + kq * 8);
        #pragma unroll
        for (int i = 0; i < 4; ++i)
            #pragma unroll
            for (int j = 0; j < 4; ++j)
                acc[i][j] = __builtin_amdgcn_mfma_f32_16x16x32_bf16(af[i], bfr[j], acc[i][j], 0, 0, 0);
        if (it + 1 < NIT) {                    // stage next tile (waits loads)
            u16* An = As + ((it + 1) & 1) * 4096;
            u16* Bn = Bs + ((it + 1) & 1) * 4096;
            *(uint4*)(An + tid * 8) = pa0;  *(uint4*)(An + 2048 + tid * 8) = pa1;
            *(uint4*)(Bn + tid * 8) = pb0;  *(uint4*)(Bn + 2048 + tid * 8) = pb1;
        }
    }
}

// ---------------------------------------------------------------------------
// Same pipeline, tile 64x128 (MLP shape), 4 waves (2m x 2n), wave 32x64.
// LDS 2*(4+8) = 24 KB.
// ---------------------------------------------------------------------------
__device__ __forceinline__ void gemm_core_pf64(const u16* __restrict__ Ab,
                                               const u16* __restrict__ Bb,
                                               u16* As /*2*2048*/, u16* Bs /*2*4096*/,
                                               int tid, f32x4 acc[2][4])
{
    const int w  = tid >> 6, l = tid & 63;
    const int wm = (w >> 1) * 32, wn = (w & 1) * 64;
    const int lr = l & 15, kq = l >> 4;
    const int row = tid >> 2, cg8 = (tid & 3) * 8;

    const u16* a0 = Ab + (size_t)row * DIM + cg8;
    const u16* b0 = Bb + (size_t)row * DIM + cg8;
    const u16* b1 = Bb + (size_t)(64 + row) * DIM + cg8;

    uint4 pa  = *(const uint4*)a0;
    uint4 pb0 = *(const uint4*)b0, pb1 = *(const uint4*)b1;
    *(uint4*)(As + tid * 8) = pa;
    *(uint4*)(Bs + tid * 8) = pb0; *(uint4*)(Bs + 2048 + tid * 8) = pb1;

    const int NIT = DIM / 32;
    for (int it = 0; it < NIT; ++it) {
        u16* Ac = As + (it & 1) * 2048;
        u16* Bc = Bs + (it & 1) * 4096;
        __syncthreads();
        if (it + 1 < NIT) {
            const int k = (it + 1) * 32;
            pa  = *(const uint4*)(a0 + k);
            pb0 = *(const uint4*)(b0 + k); pb1 = *(const uint4*)(b1 + k);
        }
        s16x8 af[2], bfr[4];
        #pragma unroll
        for (int i = 0; i < 2; ++i)
            af[i]  = *(const s16x8*)(Ac + (wm + i * 16 + lr) * 32 + kq * 8);
        #pragma unroll
        for (int j = 0; j < 4; ++j)
            bfr[j] = *(const s16x8*)(Bc + (wn + j * 16 + lr) * 32 + kq * 8);
        #pragma unroll
        for (int i = 0; i < 2; ++i)
            #pragma unroll
            for (int j = 0; j < 4; ++j)
                acc[i][j] = __builtin_amdgcn_mfma_f32_16x16x32_bf16(af[i], bfr[j], acc[i][j], 0, 0, 0);
        if (it + 1 < NIT) {
            u16* An = As + ((it + 1) & 1) * 2048;
            u16* Bn = Bs + ((it + 1) & 1) * 4096;
            *(uint4*)(An + tid * 8) = pa;
            *(uint4*)(Bn + tid * 8) = pb0; *(uint4*)(Bn + 2048 + tid * 8) = pb1;
        }
    }
}

// ---------------------------------------------------------------------------
// Fused QKV projection: grid (32 m-tiles, 24 sel*n-tiles), 256 threads.
// Consecutive blocks (x-fastest) share one weight tile (XCD L2 locality).
// ---------------------------------------------------------------------------
__global__ __launch_bounds__(256)
void qkv_gemm(const u16* __restrict__ xb,
              const u16* __restrict__ Wq, const u16* __restrict__ Wk, const u16* __restrict__ Wv,
              const float* __restrict__ bq, const float* __restrict__ bk, const float* __restrict__ bv,
              u16* __restrict__ qo, u16* __restrict__ ko, u16* __restrict__ vo)
{
    __shared__ u16 As[2 * 4096];
    __shared__ u16 Bs[2 * 4096];
    const int tid = threadIdx.x;
    const int m0  = blockIdx.x * 128;
    const int sel = blockIdx.y >> 3;
    const int n0  = (blockIdx.y & 7) * 128;
    const u16*   B    = (sel == 0) ? Wq : (sel == 1) ? Wk : Wv;
    const float* bias = (sel == 0) ? bq : (sel == 1) ? bk : bv;
    u16*         C    = (sel == 0) ? qo : (sel == 1) ? ko : vo;
    const float scale = (sel == 0) ? 0.125f : 1.0f;

    f32x4 acc[4][4];
    #pragma unroll
    for (int i = 0; i < 4; ++i)
        #pragma unroll
        for (int j = 0; j < 4; ++j) acc[i][j] = (f32x4){0.f, 0.f, 0.f, 0.f};

    gemm_core_pf128(xb + (size_t)m0 * DIM, B + (size_t)n0 * DIM, As, Bs, tid, acc);

    const int w = tid >> 6, l = tid & 63;
    const int wm = (w >> 1) * 64, wn = (w & 1) * 64;
    const int er = l >> 4, ec = l & 15;
    #pragma unroll
    for (int j = 0; j < 4; ++j) {
        const int n = n0 + wn + j * 16 + ec;
        const float bb = bias[n];
        #pragma unroll
        for (int i = 0; i < 4; ++i)
            #pragma unroll
            for (int r = 0; r < 4; ++r) {
                const int m = m0 + wm + i * 16 + er * 4 + r;
                C[(size_t)m * DIM + n] = f2bf((acc[i][j][r] + bb) * scale);
            }
    }
}

// ---------------------------------------------------------------------------
// MLP GEMMs: 256 threads, grid (64 m-tiles, 8 n-tiles) = 512 blocks, tile
// 64x128. mode 1: gelu -> bf16.   mode 2: +bias +x +attn -> fp32.
// ---------------------------------------------------------------------------
__global__ __launch_bounds__(256)
void gemm_bf16(const u16* __restrict__ A, const u16* __restrict__ B,
               const float* __restrict__ bias,
               u16* __restrict__ Cb, float* __restrict__ Cf,
               const float* __restrict__ rx, const u16* __restrict__ rattn,
               int mode)
{
    __shared__ u16 As[2 * 2048];
    __shared__ u16 Bs[2 * 4096];
    const int tid = threadIdx.x;
    const int m0 = blockIdx.x * 64, n0 = blockIdx.y * 128;

    f32x4 acc[2][4];
    #pragma unroll
    for (int i = 0; i < 2; ++i)
        #pragma unroll
        for (int j = 0; j < 4; ++j) acc[i][j] = (f32x4){0.f, 0.f, 0.f, 0.f};

    gemm_core_pf64(A + (size_t)m0 * DIM, B + (size_t)n0 * DIM, As, Bs, tid, acc);

    const int w = tid >> 6, l = tid & 63;
    const int wm = (w >> 1) * 32, wn = (w & 1) * 64;
    const int er = l >> 4, ec = l & 15;
    #pragma unroll
    for (int j = 0; j < 4; ++j) {
        const int n = n0 + wn + j * 16 + ec;
        const float bb = bias[n];
        #pragma unroll
        for (int i = 0; i < 2; ++i)
            #pragma unroll
            for (int r = 0; r < 4; ++r) {
                const int m = m0 + wm + i * 16 + er * 4 + r;
                const size_t idx = (size_t)m * DIM + n;
                float v = acc[i][j][r] + bb;
                if (mode == 1) {
                    v = 0.5f * v * (1.0f + erff(v * 0.70710678118654752f));
                    Cb[idx] = f2bf(v);
                } else {
                    Cf[idx] = v + rx[idx] + bf2f(rattn[idx]);
                }
            }
    }
}

// ---------------------------------------------------------------------------
// ktv via MFMA, no atomics. grid 256 = 32 (b,h) x 8 s-splits, 256 threads.
// ---------------------------------------------------------------------------
__global__ __launch_bounds__(256)
void ktv_mfma(const u16* __restrict__ Kb, const u16* __restrict__ Vb,
              float* __restrict__ part)
{
    __shared__ u16 Kt[64 * 264];
    __shared__ u16 Vt[64 * 264];
    const int tid = threadIdx.x;
    const int bh = blockIdx.x & 31;
    const int sp = blockIdx.x >> 5;
    const int b = bh >> 4, h = bh & 15;
    const size_t base = (size_t)b * SEQ * DIM + (size_t)h * HDIM + (size_t)sp * 256 * DIM;

    const int dg = (tid & 15) * 4;
    #pragma unroll
    for (int pass = 0; pass < 16; ++pass) {
        const int s = (tid >> 4) + 16 * pass;
        ushort4 kv = *(const ushort4*)(Kb + base + (size_t)s * DIM + dg);
        ushort4 vv = *(const ushort4*)(Vb + base + (size_t)s * DIM + dg);
        Kt[(dg + 0) * 264 + s] = kv.x; Kt[(dg + 1) * 264 + s] = kv.y;
        Kt[(dg + 2) * 264 + s] = kv.z; Kt[(dg + 3) * 264 + s] = kv.w;
        Vt[(dg + 0) * 264 + s] = vv.x; Vt[(dg + 1) * 264 + s] = vv.y;
        Vt[(dg + 2) * 264 + s] = vv.z; Vt[(dg + 3) * 264 + s] = vv.w;
    }
    __syncthreads();

    const int w = tid >> 6, l = tid & 63;
    const int lr = l & 15, kq = l >> 4;
    f32x4 acc[4];
    #pragma unroll
    for (int j = 0; j < 4; ++j) acc[j] = (f32x4){0.f, 0.f, 0.f, 0.f};

    for (int k0 = 0; k0 < 256; k0 += 32) {
        s16x8 af = *(const s16x8*)(Kt + (w * 16 + lr) * 264 + k0 + kq * 8);
        #pragma unroll
        for (int j = 0; j < 4; ++j) {
            s16x8 bf = *(const s16x8*)(Vt + (j * 16 + lr) * 264 + k0 + kq * 8);
            acc[j] = __builtin_amdgcn_mfma_f32_16x16x32_bf16(af, bf, acc[j], 0, 0, 0);
        }
    }

    float* dst = part + ((size_t)sp * 32 + bh) * (HDIM * HDIM);
    const int er = l >> 4, ec = l & 15;
    #pragma unroll
    for (int j = 0; j < 4; ++j)
        #pragma unroll
        for (int r = 0; r < 4; ++r)
            dst[(w * 16 + er * 4 + r) * HDIM + j * 16 + ec] = acc[j][r];
}

// ---------------------------------------------------------------------------
// attn = Q @ KtV (block-diag per head), fused partial-reduction.
// ---------------------------------------------------------------------------
__global__ __launch_bounds__(256)
void qktv_kernel(const u16* __restrict__ Qb, const float* __restrict__ part,
                 u16* __restrict__ attnb)
{
    __shared__ float KV[HDIM * HDIM];
    __shared__ u16 Qs[128 * 68];
    const int tid = threadIdx.x;
    const int h  = blockIdx.x;
    const int mt = blockIdx.y;
    const int row0 = mt * 128;
    const int b = row0 >> 11;
    const int bh = b * NHEAD + h;

    for (int i = tid; i < HDIM * HDIM; i += 256) {
        float s = 0.f;
        #pragma unroll
        for (int sp = 0; sp < NSPLIT; ++sp)
            s += part[((size_t)sp * 32 + bh) * (HDIM * HDIM) + i];
        KV[i] = s;
    }
    const int dg = (tid & 15) * 4;
    #pragma unroll
    for (int pass = 0; pass < 8; ++pass) {
        const int r = (tid >> 4) + 16 * pass;
        ushort4 q = *(const ushort4*)(Qb + (size_t)(row0 + r) * DIM + h * HDIM + dg);
        *(ushort4*)(Qs + r * 68 + dg) = q;
    }
    __syncthreads();

    const int tr = tid >> 3, tc = tid & 7;
    const int r0 = tr * 4, c0 = tc * 8;
    float acc[4][8] = {};
    for (int d = 0; d < HDIM; ++d) {
        float4 ka  = *(const float4*)&KV[d * HDIM + c0];
        float4 kb2 = *(const float4*)&KV[d * HDIM + c0 + 4];
        const float* k8a = (const float*)&ka;
        const float* k8b = (const float*)&kb2;
        float qv[4];
        #pragma unroll
        for (int i = 0; i < 4; ++i) qv[i] = bf2f(Qs[(r0 + i) * 68 + d]);
        #pragma unroll
        for (int i = 0; i < 4; ++i)
            #pragma unroll
            for (int j = 0; j < 4; ++j) {
                acc[i][j]     += qv[i] * k8a[j];
                acc[i][j + 4] += qv[i] * k8b[j];
            }
    }
    #pragma unroll
    for (int i = 0; i < 4; ++i) {
        u16* dst = attnb + (size_t)(row0 + r0 + i) * DIM + h * HDIM + c0;
        ushort4 o0 = { f2bf(acc[i][0]), f2bf(acc[i][1]), f2bf(acc[i][2]), f2bf(acc[i][3]) };
        ushort4 o1 = { f2bf(acc[i][4]), f2bf(acc[i][5]), f2bf(acc[i][6]), f2bf(acc[i][7]) };
        *(ushort4*)(dst)     = o0;
        *(ushort4*)(dst + 4) = o1;
    }
}

// ---------------------------------------------------------------------------
extern "C" void kernel_launch(void* const* d_in, const int* in_sizes, int n_in,
                              void* d_out, int out_size, void* d_ws, size_t ws_size,
                              hipStream_t stream)
{
    const float* x  = (const float*)d_in[0];
    const float* Wq = (const float*)d_in[1];
    const float* bq = (const float*)d_in[2];
    const float* Wk = (const float*)d_in[3];
    const float* bk = (const float*)d_in[4];
    const float* Wv = (const float*)d_in[5];
    const float* bv = (const float*)d_in[6];
    const float* W1 = (const float*)d_in[7];
    const float* b1 = (const float*)d_in[8];
    const float* W2 = (const float*)d_in[9];
    const float* b2 = (const float*)d_in[10];
    float* out = (float*)d_out;

    char* ws = (char*)d_ws;
    const size_t MB = 1u << 20;
    u16* xb   = (u16*)(ws);              //  8 MB
    u16* Wqb  = (u16*)(ws +  8 * MB);    //  2 MB each
    u16* Wkb  = (u16*)(ws + 10 * MB);
    u16* Wvb  = (u16*)(ws + 12 * MB);
    u16* W1b  = (u16*)(ws + 14 * MB);
    u16* W2b  = (u16*)(ws + 16 * MB);
    u16* qb   = (u16*)(ws + 18 * MB);    //  8 MB
    u16* kb   = (u16*)(ws + 26 * MB);    //  8 MB
    u16* vb   = (u16*)(ws + 34 * MB);    //  8 MB
    float* part = (float*)(ws + 42 * MB);//  4 MB
    u16* attnb = kb;
    u16* h1b   = vb;

    pack_all<<<4096 + 5 * 1024, 256, 0, stream>>>(x, Wq, Wk, Wv, W1, W2,
                                                  xb, Wqb, Wkb, Wvb, W1b, W2b);

    qkv_gemm<<<dim3(32, 24), 256, 0, stream>>>(xb, Wqb, Wkb, Wvb, bq, bk, bv, qb, kb, vb);

    ktv_mfma<<<NSPLIT * 32, 256, 0, stream>>>(kb, vb, part);
    qktv_kernel<<<dim3(NHEAD, MROWS / 128), 256, 0, stream>>>(qb, part, attnb);

    gemm_bf16<<<dim3(64, 8), 256, 0, stream>>>(attnb, W1b, b1, h1b, nullptr, nullptr, nullptr, 1);
    gemm_bf16<<<dim3(64, 8), 256, 0, stream>>>(h1b, W2b, b2, nullptr, out, x, attnb, 2);
}